// Round 11
// baseline (206.079 us; speedup 1.0000x reference)
//
#include <hip/hip_runtime.h>
#include <stdint.h>

// ---------------- problem constants ----------------
#define BB 2
#define SS 2048
#define EE 1024
#define HH 16
#define DHD 64
#define MM (BB*SS)          // 4096 tokens
// scale * log2(e): fold log2e into Q so softmax uses exp2 (v_exp_f32) directly
#define QSCALE (0.125f * 1.4426950408889634f)

typedef __bf16 bf16;
typedef __bf16 bf16x8 __attribute__((ext_vector_type(8)));
typedef __bf16 bf16x4 __attribute__((ext_vector_type(4)));
typedef __bf16 bf16x2 __attribute__((ext_vector_type(2)));
typedef float  f32x4  __attribute__((ext_vector_type(4)));
typedef float  f32x16 __attribute__((ext_vector_type(16)));
typedef unsigned short ushort8 __attribute__((ext_vector_type(8)));

#define MFMA16(a,b,c) __builtin_amdgcn_mfma_f32_16x16x32_bf16(a,b,c,0,0,0)
#define MFMA32(a,b,c) __builtin_amdgcn_mfma_f32_32x32x16_bf16(a,b,c,0,0,0)

__device__ __forceinline__ void gload_lds16(const void* g, void* l) {
  __builtin_amdgcn_global_load_lds(
      (const __attribute__((address_space(1))) unsigned int*)g,
      (__attribute__((address_space(3))) unsigned int*)l, 16, 0, 0);
}

__device__ __forceinline__ unsigned short f2bf(float f) {
  union { float f; unsigned u; } v; v.f = f;
  return (unsigned short)((v.u + 0x7FFFu + ((v.u >> 16) & 1u)) >> 16);
}

// ---------------- kernel 0: fp32 -> bf16 conversion ----------------
__global__ void convert_kernel(const float* __restrict__ x,
                               const float* __restrict__ wq, const float* __restrict__ wk,
                               const float* __restrict__ wv, const float* __restrict__ wo,
                               unsigned short* __restrict__ xbf,
                               unsigned short* __restrict__ wqb, unsigned short* __restrict__ wkb,
                               unsigned short* __restrict__ wvb, unsigned short* __restrict__ wob) {
  long t = (long)blockIdx.x * blockDim.x + threadIdx.x;  // 1M threads
  long base = t * 8;
  const float* src; unsigned short* dst; long off;
  if (base < 4194304L) { src = x; dst = xbf; off = base; }
  else {
    long r = base - 4194304L; int j = (int)(r >> 20); off = r & 1048575L;
    src = (j==0)?wq:(j==1)?wk:(j==2)?wv:wo;
    dst = (j==0)?wqb:(j==1)?wkb:(j==2)?wvb:wob;
  }
  const float4* s4 = (const float4*)(src + off);
  float4 a = s4[0], b = s4[1];
  ushort8 o;
  o[0]=f2bf(a.x); o[1]=f2bf(a.y); o[2]=f2bf(a.z); o[3]=f2bf(a.w);
  o[4]=f2bf(b.x); o[5]=f2bf(b.y); o[6]=f2bf(b.z); o[7]=f2bf(b.w);
  *(ushort8*)(dst + off) = o;
}

// ---- shared GEMM K-loop: 3-buffer LDS, 2-deep prefetch, SINGLE barrier (R9) ----
#define GS_STAGE(kbuf, kt) { \
    const size_t kb_ = (size_t)(kt) * 64; \
    char* d_ = lds + (kbuf) * 16384 + tid * 16; \
    gload_lds16(a0 + kb_, d_); \
    gload_lds16(a1 + kb_, d_ + 4096); \
    gload_lds16(b0 + kb_, d_ + 8192); \
    gload_lds16(b1 + kb_, d_ + 12288); \
  }

template<bool SWAP>
__device__ __forceinline__ void gemm_kloop(
    const char* a0, const char* a1, const char* b0, const char* b1,
    char* lds, const int tid, const int (&aoff)[4], const int (&boff)[4],
    f32x4 (&acc)[4][4]) {
  GS_STAGE(0, 0);
  GS_STAGE(1, 1);
  int cur = 0;
  for (int kt = 0; kt < 32; ++kt) {
    if (kt < 31) {
      asm volatile("s_waitcnt vmcnt(4)" ::: "memory");
    } else {
      asm volatile("s_waitcnt vmcnt(0)" ::: "memory");
    }
    __builtin_amdgcn_s_barrier();
    if (kt < 30) {
      int sb = cur + 2; if (sb >= 3) sb -= 3;
      GS_STAGE(sb, kt + 2);
    }
    const char* Ts = lds + cur * 16384;
    bf16x8 af[4], bfv[4];
#pragma unroll
    for (int mt=0; mt<4; ++mt) af[mt] = *(const bf16x8*)(Ts + aoff[mt]);
#pragma unroll
    for (int nt=0; nt<4; ++nt) bfv[nt] = *(const bf16x8*)(Ts + boff[nt]);
#pragma unroll
    for (int mt=0; mt<4; ++mt)
#pragma unroll
      for (int nt=0; nt<4; ++nt)
        acc[mt][nt] = SWAP ? MFMA16(bfv[nt], af[mt], acc[mt][nt])
                           : MFMA16(af[mt], bfv[nt], acc[mt][nt]);
    cur = (cur == 2) ? 0 : cur + 1;
  }
}

// ---------------- kernel 1: fused QKV projection GEMM ----------------
// 1D grid 768, XCD-locality remap: xcd = bid&7 owns x row-stripe [4*xcd*128 ..),
// sweeps 24 column-blocks with row-fastest order (W col hot for 4 blocks,
// 1MB x-stripe L2-resident per XCD).
__global__ __launch_bounds__(256) void qkv_gemm(
    const bf16* __restrict__ xbf,
    const bf16* __restrict__ wqb, const bf16* __restrict__ wkb, const bf16* __restrict__ wvb,
    const float* __restrict__ bq, const float* __restrict__ bk, const float* __restrict__ bv,
    bf16* __restrict__ Q, bf16* __restrict__ K, bf16* __restrict__ VT) {
  __shared__ char lds[49152] __attribute__((aligned(16)));
  const int tid = threadIdx.x;
  const int bid = blockIdx.x;
  const int xcd = bid & 7;
  const int ii = bid >> 3;            // [0,96)
  const int col = ii >> 2;            // [0,24)
  const int row = xcd * 4 + (ii & 3); // [0,32)
  const int bm = row * 128;
  const int bnG = col * 128;
  const int proj = bnG >> 10;
  const int bn = bnG & 1023;
  const bf16* wsel = (proj==0)?wqb:(proj==1)?wkb:wvb;
  const float* bias = (proj==0)?bq:(proj==1)?bk:bv;

  const int lane = tid & 63, w = tid >> 6;
  const int wm = (w>>1)*64, wn = (w&1)*64;
  const int c = lane & 15, g = lane >> 4;

  const int sr = tid >> 2;
  const int scb = ((tid & 3) * 16) ^ ((sr & 3) << 4);
  const char* a0 = (const char*)xbf  + ((size_t)(bm + sr     ) * 1024) * 2 + scb;
  const char* a1 = (const char*)xbf  + ((size_t)(bm + 64 + sr) * 1024) * 2 + scb;
  const char* b0 = (const char*)wsel + ((size_t)(bn + sr     ) * 1024) * 2 + scb;
  const char* b1 = (const char*)wsel + ((size_t)(bn + 64 + sr) * 1024) * 2 + scb;

  int aoff[4], boff[4];
#pragma unroll
  for (int mt=0; mt<4; ++mt) { int rr = wm + mt*16 + c; aoff[mt] = rr*64 + ((g*16) ^ ((rr&3)<<4)); }
#pragma unroll
  for (int nt=0; nt<4; ++nt) { int rr = wn + nt*16 + c; boff[nt] = 8192 + rr*64 + ((g*16) ^ ((rr&3)<<4)); }

  f32x4 acc[4][4];
#pragma unroll
  for (int mt=0; mt<4; ++mt)
#pragma unroll
    for (int nt=0; nt<4; ++nt) acc[mt][nt] = (f32x4){0.f,0.f,0.f,0.f};

  const int bidx = bm >> 11;
  const int srow = bm & 2047;

  if (proj != 2) {
    gemm_kloop<true>(a0, a1, b0, b1, lds, tid, aoff, boff, acc);
    bf16* dst = (proj == 0) ? Q : K;
    const float qs = (proj == 0) ? QSCALE : 1.0f;
#pragma unroll
    for (int nt=0; nt<4; ++nt) {
      const int n0 = bn + wn + nt*16 + g*4;
      const float4 b4 = *(const float4*)(bias + n0);
      const int h = n0 >> 6, d0 = n0 & 63;
#pragma unroll
      for (int mt=0; mt<4; ++mt) {
        const int s = srow + wm + mt*16 + c;
        bf16x4 pk;
        pk[0] = (bf16)((acc[mt][nt][0] + b4.x) * qs);
        pk[1] = (bf16)((acc[mt][nt][1] + b4.y) * qs);
        pk[2] = (bf16)((acc[mt][nt][2] + b4.z) * qs);
        pk[3] = (bf16)((acc[mt][nt][3] + b4.w) * qs);
        *(bf16x4*)(dst + (((size_t)(bidx*16 + h))*2048 + s)*64 + d0) = pk;
      }
    }
  } else {
    gemm_kloop<false>(a0, a1, b0, b1, lds, tid, aoff, boff, acc);
#pragma unroll
    for (int nt=0; nt<4; ++nt) {
      const int n = bn + wn + nt*16 + c;
      const float bv_ = bias[n];
      const int h = n >> 6, d = n & 63;
#pragma unroll
      for (int mt=0; mt<4; ++mt) {
        const int m0 = wm + mt*16 + g*4;
        bf16x4 pk;
#pragma unroll
        for (int r=0;r<4;++r) pk[r] = (bf16)(acc[mt][nt][r] + bv_);
        *(bf16x4*)(VT + (((size_t)(bidx*16 + h))*64 + d)*2048 + (srow + m0)) = pk;
      }
    }
  }
}

// ---------------- kernel 2: flash attention v5 — 4 waves x 32q, 32x32 MFMA ----------------
// 1D grid 512 (2 blocks/CU for cross-block latency overlap), XCD remap co-locates
// each head's 16 q-blocks (per-XCD K/V working set 4 heads x 512KB = 2MB, L2-fit).
// Inner math identical to verified R10 v4. Single-barrier dbuf loop.
__global__ __launch_bounds__(256) void attn_kernel(
    const bf16* __restrict__ Q, const bf16* __restrict__ K,
    const bf16* __restrict__ VT, bf16* __restrict__ attn_out) {
  __shared__ char alds[32768] __attribute__((aligned(16)));
  const int tid = threadIdx.x;
  const int bid = blockIdx.x;
  const int xcd = bid & 7;
  const int ii = bid >> 3;            // [0,64)
  const int bh = (ii >> 4) * 8 + xcd; // [0,32): 4 heads per XCD, q-blocks consecutive
  const int qbase = (ii & 15) * 128;
  const int L = tid & 63, wid = tid >> 6;   // wid in [0,4)
  const int q5 = L & 31, h = L >> 5;
  const bf16* Qh = Q + (size_t)bh * 2048 * 64;
  const char* Khb = (const char*)(K  + (size_t)bh * 2048 * 64);
  const char* Vhb = (const char*)(VT + (size_t)bh * 64 * 2048);

  // staging (256 thr x 16B = 4KB per instr, 4 instr per 16KB K+V tile):
  // LDS(row, ch) <- global(row, ch ^ (row&7)); row = tid>>3 in [0,32), ch = tid&7
  const int srow = tid >> 3, sch = tid & 7;
  const int ssw = ((sch ^ (srow & 7)) << 4);
  const char* srcK = Khb + (size_t)srow * 128  + ssw;   // + kv*128
  const char* srcV = Vhb + (size_t)srow * 4096 + ssw;   // + kv*2

#define ATT_STAGE(buf, kv) { \
    const char* sk_ = srcK + (size_t)(kv) * 128; \
    const char* sv_ = srcV + (size_t)(kv) * 2; \
    char* d_ = alds + (buf) * 16384 + tid * 16; \
    gload_lds16(sk_,           d_); \
    gload_lds16(sk_ + 32*128,  d_ + 4096); \
    gload_lds16(sv_,           d_ + 8192); \
    gload_lds16(sv_ + 32*4096, d_ + 12288); \
  }

  // Q fragments (B-operand): lane -> q = qbase + wid*32 + q5, k = 8h+e over d-window 16*dk
  const int qrow = qbase + wid * 32 + q5;
  bf16x8 qf[4];
#pragma unroll
  for (int dk = 0; dk < 4; ++dk)
    qf[dk] = *(const bf16x8*)(Qh + (size_t)qrow * 64 + dk * 16 + h * 8);

  f32x16 o0 = {0,0,0,0,0,0,0,0,0,0,0,0,0,0,0,0};
  f32x16 o1 = {0,0,0,0,0,0,0,0,0,0,0,0,0,0,0,0};
  float m = -1e30f, l = 0.f;

  ATT_STAGE(0, 0);
  asm volatile("s_waitcnt vmcnt(0)" ::: "memory");
  __builtin_amdgcn_s_barrier();

  for (int t = 0; t < 32; ++t) {
    const int cur = t & 1;
    if (t < 31) ATT_STAGE(cur ^ 1, (t + 1) * 64);

    const char* Kl = alds + cur * 16384;
    const char* Vl = Kl + 8192;

    // QK^T: st_s = scores for keys s*32 + (r&3)+8*(r>>2)+4h, q = q5
    f32x16 st0 = {0,0,0,0,0,0,0,0,0,0,0,0,0,0,0,0};
    f32x16 st1 = {0,0,0,0,0,0,0,0,0,0,0,0,0,0,0,0};
#pragma unroll
    for (int dk = 0; dk < 4; ++dk) {
      const int r0 = q5;            // A rows: keys 0-31
      bf16x8 k0 = *(const bf16x8*)(Kl + r0*128 + (((2*dk + h) ^ (r0 & 7)) << 4));
      const int r1 = 32 + q5;       // A rows: keys 32-63
      bf16x8 k1 = *(const bf16x8*)(Kl + r1*128 + (((2*dk + h) ^ (r1 & 7)) << 4));
      st0 = MFMA32(k0, qf[dk], st0);
      st1 = MFMA32(k1, qf[dk], st1);
    }

    // in-lane max over 32 + pair reduce
    float tmax = -1e30f;
#pragma unroll
    for (int r = 0; r < 16; ++r) { tmax = fmaxf(tmax, st0[r]); tmax = fmaxf(tmax, st1[r]); }
    tmax = fmaxf(tmax, __shfl_xor(tmax, 32, 64));
    if (!__all(tmax <= m + 8.f)) {                 // defer-max (THR=8)
      const float mnew = fmaxf(m, tmax);
      const float corr = __builtin_exp2f(m - mnew);
      l *= corr;
      o0 *= corr; o1 *= corr;
      m = mnew;
    }

    // exp2 + pack pairs: pkS[j][a] = bf16x2(p[4j+2a], p[4j+2a+1]) = keys 32s+8j+4h+2a+{0,1}
    unsigned pk0[4][2], pk1[4][2];
    float ps = 0.f;
#pragma unroll
    for (int j = 0; j < 4; ++j)
#pragma unroll
      for (int a = 0; a < 2; ++a) {
        {
          float x0 = __builtin_exp2f(st0[4*j+2*a]     - m);
          float x1 = __builtin_exp2f(st0[4*j+2*a + 1] - m);
          ps += x0 + x1;
          union { bf16x2 v; unsigned u; } z; z.v[0] = (bf16)x0; z.v[1] = (bf16)x1;
          pk0[j][a] = z.u;
        }
        {
          float x0 = __builtin_exp2f(st1[4*j+2*a]     - m);
          float x1 = __builtin_exp2f(st1[4*j+2*a + 1] - m);
          ps += x0 + x1;
          union { bf16x2 v; unsigned u; } z; z.v[0] = (bf16)x0; z.v[1] = (bf16)x1;
          pk1[j][a] = z.u;
        }
      }
    ps += __shfl_xor(ps, 32, 64);
    l += ps;

    // Assemble PV B-frags: frag c covers keys 16c+8h+{0..7} for this lane.
    bf16x8 pf[4];
#pragma unroll
    for (int c = 0; c < 4; ++c) {
      const int cl = c & 1;
      unsigned own0, own1, snd0, snd1;
      if (c < 2) {
        own0 = h ? pk0[2*cl+1][0] : pk0[2*cl][0];
        own1 = h ? pk0[2*cl+1][1] : pk0[2*cl][1];
        snd0 = h ? pk0[2*cl][0]   : pk0[2*cl+1][0];
        snd1 = h ? pk0[2*cl][1]   : pk0[2*cl+1][1];
      } else {
        own0 = h ? pk1[2*cl+1][0] : pk1[2*cl][0];
        own1 = h ? pk1[2*cl+1][1] : pk1[2*cl][1];
        snd0 = h ? pk1[2*cl][0]   : pk1[2*cl+1][0];
        snd1 = h ? pk1[2*cl][1]   : pk1[2*cl+1][1];
      }
      unsigned sx0 = (unsigned)__shfl_xor((int)snd0, 32, 64);
      unsigned sx1 = (unsigned)__shfl_xor((int)snd1, 32, 64);
      union { unsigned u[4]; bf16x8 v; } fr;
      fr.u[0] = h ? sx0 : own0;
      fr.u[1] = h ? sx1 : own1;
      fr.u[2] = h ? own0 : sx0;
      fr.u[3] = h ? own1 : sx1;
      pf[c] = fr.v;
    }

    // PV: o_dblk += V^T[d = 32*dblk + rows][keys 16c+8h+e] x P
#pragma unroll
    for (int c = 0; c < 4; ++c) {
      const int r0 = q5;            // d rows 0-31
      bf16x8 v0 = *(const bf16x8*)(Vl + r0*128 + (((2*c + h) ^ (r0 & 7)) << 4));
      const int r1 = 32 + q5;       // d rows 32-63
      bf16x8 v1 = *(const bf16x8*)(Vl + r1*128 + (((2*c + h) ^ (r1 & 7)) << 4));
      o0 = MFMA32(v0, pf[c], o0);
      o1 = MFMA32(v1, pf[c], o1);
    }

    if (t < 31) {
      asm volatile("s_waitcnt vmcnt(0)" ::: "memory");   // stage(t+1) landed
      __builtin_amdgcn_s_barrier();
    }
  }
#undef ATT_STAGE

  // epilogue: D layout col=q5, row = (r&3)+8*(r>>2)+4h (+32 for o1)
  const float inv = 1.0f / l;
  const int b = bh >> 4, hh = bh & 15;
  bf16* outrow = attn_out + ((size_t)(b*2048 + qrow))*1024 + hh*64;
#pragma unroll
  for (int j = 0; j < 4; ++j) {
    bf16x4 ov;
#pragma unroll
    for (int i = 0; i < 4; ++i) ov[i] = (bf16)(o0[4*j+i] * inv);
    *(bf16x4*)(outrow + 8*j + 4*h) = ov;
#pragma unroll
    for (int i = 0; i < 4; ++i) ov[i] = (bf16)(o1[4*j+i] * inv);
    *(bf16x4*)(outrow + 32 + 8*j + 4*h) = ov;
  }
}

// ---------------- kernel 3: output projection GEMM ----------------
// 1D grid 512, XCD remap: xcd owns 8 bm-blocks (1MB attnb stripe), sweeps 8
// W-columns row-fastest. 64x128 tile, single-barrier 2-deep loop, float4 stores.
__global__ __launch_bounds__(256) void out_gemm(
    const bf16* __restrict__ A, const bf16* __restrict__ W,
    const float* __restrict__ bias, float* __restrict__ out) {
  __shared__ char lds[36864] __attribute__((aligned(16)));
  const int tid = threadIdx.x;
  const int bid = blockIdx.x;
  const int xcd = bid & 7;
  const int ii = bid >> 3;            // [0,64)
  const int col = ii >> 3;            // [0,8)
  const int rowb = xcd * 8 + (ii & 7);// [0,64)
  const int bm = rowb * 64, bn = col * 128;
  const int lane = tid & 63, w = tid >> 6;
  const int c = lane & 15, g = lane >> 4;

  const int sr = tid >> 2;
  const int scb = ((tid & 3) * 16) ^ ((sr & 3) << 4);
  const char* a0 = (const char*)A + ((size_t)(bm + sr     ) * 1024) * 2 + scb;
  const char* b0 = (const char*)W + ((size_t)(bn + sr     ) * 1024) * 2 + scb;
  const char* b1 = (const char*)W + ((size_t)(bn + 64 + sr) * 1024) * 2 + scb;

#define OUT_STAGE(kbuf, kt) { \
    const size_t kb_ = (size_t)(kt) * 64; \
    char* d_ = lds + (kbuf) * 12288 + tid * 16; \
    gload_lds16(a0 + kb_, d_); \
    gload_lds16(b0 + kb_, d_ + 4096); \
    gload_lds16(b1 + kb_, d_ + 8192); \
  }

  int aoff[4], boff[2];
#pragma unroll
  for (int mt=0; mt<4; ++mt) { int rr = mt*16 + c; aoff[mt] = rr*64 + ((g*16) ^ ((rr&3)<<4)); }
#pragma unroll
  for (int nt=0; nt<2; ++nt) { int rr = w*32 + nt*16 + c; boff[nt] = 4096 + rr*64 + ((g*16) ^ ((rr&3)<<4)); }

  f32x4 acc[4][2];
#pragma unroll
  for (int mt=0; mt<4; ++mt)
#pragma unroll
    for (int nt=0; nt<2; ++nt) acc[mt][nt] = (f32x4){0.f,0.f,0.f,0.f};

  OUT_STAGE(0, 0);
  OUT_STAGE(1, 1);
  int cur = 0;
  for (int kt = 0; kt < 32; ++kt) {
    if (kt < 31) {
      asm volatile("s_waitcnt vmcnt(3)" ::: "memory");
    } else {
      asm volatile("s_waitcnt vmcnt(0)" ::: "memory");
    }
    __builtin_amdgcn_s_barrier();
    if (kt < 30) {
      int sb = cur + 2; if (sb >= 3) sb -= 3;
      OUT_STAGE(sb, kt + 2);
    }
    const char* Ts = lds + cur * 12288;
    bf16x8 af[4], bfv[2];
#pragma unroll
    for (int mt=0; mt<4; ++mt) af[mt] = *(const bf16x8*)(Ts + aoff[mt]);
#pragma unroll
    for (int nt=0; nt<2; ++nt) bfv[nt] = *(const bf16x8*)(Ts + boff[nt]);
#pragma unroll
    for (int mt=0; mt<4; ++mt)
#pragma unroll
      for (int nt=0; nt<2; ++nt)
        acc[mt][nt] = MFMA16(bfv[nt], af[mt], acc[mt][nt]);
    cur = (cur == 2) ? 0 : cur + 1;
  }
#undef OUT_STAGE

#pragma unroll
  for (int nt=0; nt<2; ++nt) {
    const int n0 = bn + w*32 + nt*16 + g*4;
    const float4 b4 = *(const float4*)(bias + n0);
#pragma unroll
    for (int mt=0; mt<4; ++mt) {
      const int m0 = bm + mt*16 + c;
      float4 ov;
      ov.x = acc[mt][nt][0] + b4.x;
      ov.y = acc[mt][nt][1] + b4.y;
      ov.z = acc[mt][nt][2] + b4.z;
      ov.w = acc[mt][nt][3] + b4.w;
      *(float4*)(out + (size_t)m0*1024 + n0) = ov;
    }
  }
}

// ---------------- launch ----------------
extern "C" void kernel_launch(void* const* d_in, const int* in_sizes, int n_in,
                              void* d_out, int out_size, void* d_ws, size_t ws_size,
                              hipStream_t stream) {
  const float* x  = (const float*)d_in[0];
  const float* Wq = (const float*)d_in[1];
  const float* bq = (const float*)d_in[2];
  const float* Wk = (const float*)d_in[3];
  const float* bk = (const float*)d_in[4];
  const float* Wv = (const float*)d_in[5];
  const float* bv = (const float*)d_in[6];
  const float* Wo = (const float*)d_in[7];
  const float* bo = (const float*)d_in[8];

  char* ws = (char*)d_ws;
  const size_t MiB = 1u << 20;
  unsigned short* xbf = (unsigned short*)(ws);              // 8 MiB
  unsigned short* wqb = (unsigned short*)(ws +  8*MiB);     // 2 MiB
  unsigned short* wkb = (unsigned short*)(ws + 10*MiB);
  unsigned short* wvb = (unsigned short*)(ws + 12*MiB);
  unsigned short* wob = (unsigned short*)(ws + 14*MiB);
  bf16* Qb    = (bf16*)(ws + 16*MiB);                       // 8 MiB [B,H,S,DH]
  bf16* Kb    = (bf16*)(ws + 24*MiB);                       // 8 MiB [B,H,S,DH]
  bf16* VTb   = (bf16*)(ws + 32*MiB);                       // 8 MiB [B,H,DH,S]
  bf16* attnb = (bf16*)(ws + 40*MiB);                       // 8 MiB [M,E]

  convert_kernel<<<4096, 256, 0, stream>>>(x, Wq, Wk, Wv, Wo, xbf, wqb, wkb, wvb, wob);
  qkv_gemm<<<768, 256, 0, stream>>>(
      (const bf16*)xbf, (const bf16*)wqb, (const bf16*)wkb, (const bf16*)wvb,
      bq, bk, bv, Qb, Kb, VTb);
  attn_kernel<<<512, 256, 0, stream>>>(Qb, Kb, VTb, attnb);
  out_gemm<<<512, 256, 0, stream>>>(attnb, (const bf16*)wob, bo, (float*)d_out);
}